// Round 3
// 86.591 us; speedup vs baseline: 1.0014x; 1.0014x over previous
//
#include <hip/hip_runtime.h>
#include <hip/hip_bf16.h>

// SimCLR NT-Xent loss. B=4096, D=256, N=2B=8192 rows.
// loss = (1/N) sum_i [ log(denom_i) - log(pos_i) ]
//   denom_i = sum_{j!=i} exp(2*sim_ij),  pos_i = cos(z_i, z_{i+-B}) (fp32 path)
//
// R15 = R13 resubmitted verbatim, third attempt (R13/R14 both lost to
// "MI355X container failed twice" infra errors — no timing block, no compile
// or pytest verdict; source re-audited twice for container-killers: none).
// Theory under test: ~790K device-scope f32 atomicAdds (row+col sums into
// denom[8192]) are the unexplained ~20 us of R12's 86.7.
// Replacement: single-writer tile-partial array P[64][64][128] f32 (2 MB):
//   slot (x,y), x<=y : row-partials of tile (x,y)
//   slot (x,y), x>y  : col-partials of tile (y,x)
// Every slot written exactly once by exactly one tile -> no init, no atomics.
// denom_i = sum_k P[i>>7][k][i&127], folded into loss_kernel (coalesced,
// L2-resident). Block schedule / staging / MFMA path bit-identical to R12
// (R11 lesson: do not touch the 2080-block 3-per-CU schedule).

#define NROWS 8192
#define BHALF 4096
#define DDIM  256

typedef __attribute__((ext_vector_type(4))) int   i32x4;
typedef __attribute__((ext_vector_type(8))) int   i32x8;
typedef __attribute__((ext_vector_type(4))) float f32x4;

#define SCALE1 0x7F7F7F7F               // e8m0 biased-127 = 2^0 in every byte
#define TWO_LOG2E 2.8853900817779268f   // 2/ln(2): exp(2x) = exp2(x*TWO_LOG2E)

__device__ __forceinline__ void load_lds16(const unsigned char* g, unsigned char* l) {
    __builtin_amdgcn_global_load_lds(
        (const __attribute__((address_space(1))) void*)g,
        (__attribute__((address_space(3))) void*)l, 16, 0, 0);
}

// Kernel 1: norms + fp8-normalized matrix + positive-pair log partials +
// out zero-init. (denom zero-init deleted — P needs no init.)
__global__ __launch_bounds__(256) void prep_kernel(const float* __restrict__ z1,
                                                   const float* __restrict__ z2,
                                                   unsigned char* __restrict__ zn8,
                                                   float* __restrict__ posPart,
                                                   float* __restrict__ out) {
    __shared__ float sp[4];
    int wave = threadIdx.x >> 6;
    int lane = threadIdx.x & 63;
    int i    = blockIdx.x * 4 + wave;
    float4 a = reinterpret_cast<const float4*>(z1 + (size_t)i * DDIM)[lane];
    float4 b = reinterpret_cast<const float4*>(z2 + (size_t)i * DDIM)[lane];
    float ss1 = a.x * a.x + a.y * a.y + a.z * a.z + a.w * a.w;
    float ss2 = b.x * b.x + b.y * b.y + b.z * b.z + b.w * b.w;
    float dd  = a.x * b.x + a.y * b.y + a.z * b.z + a.w * b.w;
    #pragma unroll
    for (int off = 32; off; off >>= 1) {
        ss1 += __shfl_xor(ss1, off);
        ss2 += __shfl_xor(ss2, off);
        dd  += __shfl_xor(dd, off);
    }
    float n1 = fmaxf(sqrtf(ss1), 1e-8f);
    float n2 = fmaxf(sqrtf(ss2), 1e-8f);
    float i1 = 1.0f / n1, i2 = 1.0f / n2;
    int pa = __builtin_amdgcn_cvt_pk_fp8_f32(a.x * i1, a.y * i1, 0, 0);
    pa     = __builtin_amdgcn_cvt_pk_fp8_f32(a.z * i1, a.w * i1, pa, 1);
    int pb = __builtin_amdgcn_cvt_pk_fp8_f32(b.x * i2, b.y * i2, 0, 0);
    pb     = __builtin_amdgcn_cvt_pk_fp8_f32(b.z * i2, b.w * i2, pb, 1);
    reinterpret_cast<int*>(zn8 + (size_t)i * DDIM)[lane] = pa;
    reinterpret_cast<int*>(zn8 + (size_t)(i + BHALF) * DDIM)[lane] = pb;
    if (lane == 0) sp[wave] = __logf(dd * i1 * i2);
    if (blockIdx.x == 0 && threadIdx.x == 64) out[0] = 0.0f;
    __syncthreads();
    if (threadIdx.x == 0)
        posPart[blockIdx.x] = sp[0] + sp[1] + sp[2] + sp[3];
}

// Kernel 2: fp8 MFMA sim-GEMM + exp row/col-sums, upper-triangular 128x128
// tiles. LDS 48 KB: A(32 KB, consumed to regs) aliased by B1(16 KB) + B0(16 KB).
// Outputs: plain stores of per-tile partial sums into P (no atomics).
__global__ __launch_bounds__(256, 3) void denom_kernel(const unsigned char* __restrict__ zn8,
                                                       float* __restrict__ P) {
    __shared__ __align__(16) unsigned char sMem[48 * 1024];
    unsigned char* sA  = sMem;            // 32 KB, read into regs then dead
    unsigned char* sB0 = sMem + 32768;    // 16 KB
    unsigned char* sB1 = sMem;            // aliases A's first 16 KB
    // scratch (dead after A-frag reads, disjoint from sB0/sB1):
    float* red    = (float*)(sMem + 16384);  // 256 f32: row partials (wn pair)
    float* colRed = red + 256;               // 256 f32: col partials (wm pair)

    // triangular decode: 65x32 grid -> {(bi,bj) : 0 <= bi <= bj < 64}
    int x = blockIdx.x, y = blockIdx.y;
    int bi, bj;
    if (x > y) { bi = y;      bj = x - 1;  }
    else       { bi = 63 - y; bj = 63 - x; }
    int iBase = bi * 128;
    int jBase = bj * 128;
    bool isDiag = (bi == bj);

    int t    = threadIdx.x;
    int lane = t & 63;
    int wave = t >> 6;
    int col  = lane & 15;
    int quad = lane >> 4;
    int wm = wave >> 1, wn = wave & 1;

    // staging addresses (granule id = q*256 + t; row = q*16 + rowL;
    // slot pos (t&15) holds k-chunk (t&15)^rowL — verified XOR swizzle)
    int rowL  = t >> 4;
    int chunk = (t & 15) ^ rowL;

    // ---- stage A (128 rows) + B half 0 (64 rows) ----
    {
        const unsigned char* gA = zn8 + (size_t)(iBase + rowL) * DDIM + chunk * 16;
        #pragma unroll
        for (int q = 0; q < 8; q++)
            load_lds16(gA + q * 4096, sA + t * 16 + q * 4096);
        const unsigned char* gB = zn8 + (size_t)(jBase + rowL) * DDIM + chunk * 16;
        #pragma unroll
        for (int q = 0; q < 4; q++)
            load_lds16(gB + q * 4096, sB0 + t * 16 + q * 4096);
    }
    __syncthreads();

    // ---- A-fragments -> registers (once per tile) ----
    i32x8 af[4][2];
    {
        const unsigned char* aRow = sA + (size_t)(wm * 64 + col) * DDIM;
        #pragma unroll
        for (int mt = 0; mt < 4; mt++)
            #pragma unroll
            for (int ks = 0; ks < 2; ks++) {
                int g0 = ks * 8 + quad * 2;
                i32x4 lo = *(const i32x4*)(aRow + mt * 16 * DDIM + ((g0    ) ^ col) * 16);
                i32x4 hi = *(const i32x4*)(aRow + mt * 16 * DDIM + ((g0 + 1) ^ col) * 16);
                af[mt][ks] = __builtin_shufflevector(lo, hi, 0, 1, 2, 3, 4, 5, 6, 7);
            }
    }
    __syncthreads();   // all waves done with sA (lgkm-only drain: cheap)

    // ---- prefetch B half 1 into sB1 (flies during half-0 compute) ----
    {
        const unsigned char* gB = zn8 + (size_t)(jBase + 64 + rowL) * DDIM + chunk * 16;
        #pragma unroll
        for (int q = 0; q < 4; q++)
            load_lds16(gB + q * 4096, sB1 + t * 16 + q * 4096);
    }

    float rs[4][4];                     // row-sums, accumulated over both halves
    #pragma unroll
    for (int mt = 0; mt < 4; mt++)
        #pragma unroll
        for (int r = 0; r < 4; r++) rs[mt][r] = 0.f;

    #pragma unroll
    for (int h = 0; h < 2; h++) {
        if (h) __syncthreads();          // drains B1 (issued one compute phase ago)
        const unsigned char* bRow =
            (h ? sB1 : sB0) + (size_t)(wn * 32 + col) * DDIM;

        // B fragments: row' = wn*32 + nt*16 + col (row'&15 == col)
        i32x8 bfr[2][2];
        #pragma unroll
        for (int nt = 0; nt < 2; nt++)
            #pragma unroll
            for (int ks = 0; ks < 2; ks++) {
                int g0 = ks * 8 + quad * 2;
                i32x4 lo = *(const i32x4*)(bRow + nt * 16 * DDIM + ((g0    ) ^ col) * 16);
                i32x4 hi = *(const i32x4*)(bRow + nt * 16 * DDIM + ((g0 + 1) ^ col) * 16);
                bfr[nt][ks] = __builtin_shufflevector(lo, hi, 0, 1, 2, 3, 4, 5, 6, 7);
            }

        float cs[2] = {0.f, 0.f};
        #pragma unroll
        for (int mt = 0; mt < 4; mt++) {
            int gi = iBase + wm * 64 + mt * 16;
            #pragma unroll
            for (int nt = 0; nt < 2; nt++) {
                f32x4 acc = {0.f, 0.f, 0.f, 0.f};
                acc = __builtin_amdgcn_mfma_scale_f32_16x16x128_f8f6f4(
                          af[mt][0], bfr[nt][0], acc, 0, 0, 0, SCALE1, 0, SCALE1);
                acc = __builtin_amdgcn_mfma_scale_f32_16x16x128_f8f6f4(
                          af[mt][1], bfr[nt][1], acc, 0, 0, 0, SCALE1, 0, SCALE1);
                bool dtile = (gi == jBase + h * 64 + wn * 32 + nt * 16);
                float csl = 0.f;
                #pragma unroll
                for (int r = 0; r < 4; r++) {
                    float e = exp2f(acc[r] * TWO_LOG2E);
                    if (dtile && (quad * 4 + r) == col) e = 0.f;
                    rs[mt][r] += e;
                    csl += e;
                }
                cs[nt] += csl;
            }
        }

        // col-sums for this half (off-diag tiles only): reduce over quads,
        // park in LDS scratch (single writer per slot — no atomics).
        if (!isDiag) {
            #pragma unroll
            for (int nt = 0; nt < 2; nt++) {
                float v = cs[nt];
                v += __shfl_xor(v, 16);
                v += __shfl_xor(v, 32);
                if (quad == 0)
                    colRed[wm * 128 + h * 64 + wn * 32 + nt * 16 + col] = v;
            }
        }
    }

    // ---- row-sums: reduce 16 col-lanes, combine wn pair via LDS ----
    #pragma unroll
    for (int mt = 0; mt < 4; mt++)
        #pragma unroll
        for (int r = 0; r < 4; r++) {
            float v = rs[mt][r];
            v += __shfl_xor(v, 1);
            v += __shfl_xor(v, 2);
            v += __shfl_xor(v, 4);
            v += __shfl_xor(v, 8);
            rs[mt][r] = v;
        }
    __syncthreads();                     // all compute reads done
    if (col == 0) {
        #pragma unroll
        for (int mt = 0; mt < 4; mt++)
            #pragma unroll
            for (int r = 0; r < 4; r++)
                red[wn * 128 + wm * 64 + mt * 16 + quad * 4 + r] = rs[mt][r];
    }
    __syncthreads();
    if (t < 128) {
        // single-writer slots: P[bi][bj][*] = row partials of this tile
        float* Prow = P + (((size_t)bi * 64 + bj) << 7);
        Prow[t] = red[t] + red[128 + t];
        if (!isDiag) {
            // P[bj][bi][*] = col partials of this tile (bj > bi here)
            float* Pcol = P + (((size_t)bj * 64 + bi) << 7);
            Pcol[t] = colRed[t] + colRed[128 + t];
        }
    }
}

// Kernel 3: per-row 64-slot reduction of P (coalesced, L2-resident) + final
// loss reduction, 32 blocks, atomic into prep-zeroed out[0].
__global__ __launch_bounds__(256) void loss_kernel(const float* __restrict__ posPart,
                                                   const float* __restrict__ P,
                                                   float* __restrict__ out) {
    __shared__ float sdata[4];
    int t = threadIdx.x;
    int i = blockIdx.x * 256 + t;
    int bi = i >> 7, r = i & 127;
    const float* p = P + ((size_t)bi << 13) + r;   // bi*64*128 + r
    float d0 = 0.f, d1 = 0.f, d2 = 0.f, d3 = 0.f;
    #pragma unroll
    for (int k = 0; k < 64; k += 4) {
        d0 += p[(k + 0) << 7];
        d1 += p[(k + 1) << 7];
        d2 += p[(k + 2) << 7];
        d3 += p[(k + 3) << 7];
    }
    float s = __logf((d0 + d1) + (d2 + d3));
    if (t < 32) s -= 2.0f * posPart[blockIdx.x * 32 + t];
    #pragma unroll
    for (int off = 32; off; off >>= 1) s += __shfl_xor(s, off);
    if ((t & 63) == 0) sdata[t >> 6] = s;
    __syncthreads();
    if (t == 0)
        atomicAdd(out, (sdata[0] + sdata[1] + sdata[2] + sdata[3]) * (1.0f / NROWS));
}

extern "C" void kernel_launch(void* const* d_in, const int* in_sizes, int n_in,
                              void* d_out, int out_size, void* d_ws, size_t ws_size,
                              hipStream_t stream) {
    const float* z1 = (const float*)d_in[0];
    const float* z2 = (const float*)d_in[1];

    // ws: zn8 fp8 [8192*256] (2 MB) | P f32[64][64][128] (2 MB) | posPart f32[1024]
    unsigned char* zn8 = (unsigned char*)d_ws;
    float* P       = (float*)((char*)d_ws + (size_t)NROWS * DDIM);
    float* posPart = P + 64 * 64 * 128;

    prep_kernel<<<BHALF / 4, 256, 0, stream>>>(z1, z2, zn8, posPart, (float*)d_out);
    denom_kernel<<<dim3(65, 32), 256, 0, stream>>>(zn8, P);
    loss_kernel<<<NROWS / 256, 256, 0, stream>>>(posPart, P, (float*)d_out);
}